// Round 3
// baseline (1412.043 us; speedup 1.0000x reference)
//
#include <hip/hip_runtime.h>
#include <hip/hip_bf16.h>
#include <cstdint>

// ---------------------------------------------------------------------------
// MultiHeadAttention: B=2, T=2048, D=1024, H=16, hd=64, causal.
// Inputs (fp32): x[B,T,D], W_qkv[3D,D], b_qkv[3D], W_out[D,D], b_out[D]
// out (fp32): [B,T,D]   (threshold = 2% of ref absmax -> bf16 compute OK)
// ws: Q[2,16,2048,64] bf16 @0 (pre-scaled 0.125), K @8MB, V @16MB, O bf16 @24MB
// ---------------------------------------------------------------------------

using short8  = __attribute__((ext_vector_type(8))) short;
using floatx4 = __attribute__((ext_vector_type(4))) float;

#define LDS_STRIDE 40  // 32 + 8 pad: 80B rows, 16B-aligned, 2-way bank alias (free)

__device__ __forceinline__ float bf16_to_f32(unsigned short u) {
    union { unsigned int i; float f; } v; v.i = ((unsigned int)u) << 16; return v.f;
}
__device__ __forceinline__ unsigned short f32_to_bf16(float f) {
    union { float f; unsigned int i; } v; v.f = f;
    unsigned int x = v.i;
    unsigned int r = x + 0x7FFFu + ((x >> 16) & 1u);  // RNE
    return (unsigned short)(r >> 16);
}
// load 8 fp32, convert to 8 bf16
__device__ __forceinline__ short8 cvt8(const float* __restrict__ p) {
    const float4 f0 = *(const float4*)p;
    const float4 f1 = *(const float4*)(p + 4);
    short8 r;
    r[0] = (short)f32_to_bf16(f0.x); r[1] = (short)f32_to_bf16(f0.y);
    r[2] = (short)f32_to_bf16(f0.z); r[3] = (short)f32_to_bf16(f0.w);
    r[4] = (short)f32_to_bf16(f1.x); r[5] = (short)f32_to_bf16(f1.y);
    r[6] = (short)f32_to_bf16(f1.z); r[7] = (short)f32_to_bf16(f1.w);
    return r;
}

// C[M,N] = A[M,K] @ W[N,K]^T + bias[N].  W,bias fp32; A fp32 (AFP32=1) or bf16.
// MODE 0: scatter into Q/K/V [2,16,2048,64] bf16; Q scaled by 0.125
// MODE 1: fp32 store to Cout[M,N]
template <int MODE, int AFP32>
__global__ __launch_bounds__(256, 2) void gemm_bt(
    const void* __restrict__ Av, const float* __restrict__ W,
    const float* __restrict__ bias,
    ushort* __restrict__ Cq, ushort* __restrict__ Ck, ushort* __restrict__ Cv,
    float* __restrict__ Cout, int M, int N, int K)
{
    __shared__ __align__(16) ushort As[128 * LDS_STRIDE];
    __shared__ __align__(16) ushort Bs[128 * LDS_STRIDE];

    const int tid  = threadIdx.x;
    const int lane = tid & 63;
    const int wave = tid >> 6;
    const int wm = (wave >> 1) * 64;
    const int wn = (wave & 1) * 64;
    const int m0 = blockIdx.x * 128;
    const int n0 = blockIdx.y * 128;
    const int quad = lane >> 4;
    const int l16  = lane & 15;

    floatx4 acc[4][4];
#pragma unroll
    for (int i = 0; i < 4; i++)
#pragma unroll
        for (int j = 0; j < 4; j++) acc[i][j] = (floatx4)0.0f;

    const int srow = tid >> 2;       // 0..63
    const int scol = (tid & 3) * 8;  // 0,8,16,24

    for (int k0 = 0; k0 < K; k0 += 32) {
        short8 a0, a1;
        if (AFP32) {
            const float* A = (const float*)Av;
            a0 = cvt8(A + (size_t)(m0 + srow) * K + k0 + scol);
            a1 = cvt8(A + (size_t)(m0 + srow + 64) * K + k0 + scol);
        } else {
            const ushort* A = (const ushort*)Av;
            a0 = *(const short8*)(A + (size_t)(m0 + srow) * K + k0 + scol);
            a1 = *(const short8*)(A + (size_t)(m0 + srow + 64) * K + k0 + scol);
        }
        const short8 b0 = cvt8(W + (size_t)(n0 + srow) * K + k0 + scol);
        const short8 b1 = cvt8(W + (size_t)(n0 + srow + 64) * K + k0 + scol);
        __syncthreads();  // previous iter's LDS reads done
        *(short8*)&As[srow * LDS_STRIDE + scol] = a0;
        *(short8*)&As[(srow + 64) * LDS_STRIDE + scol] = a1;
        *(short8*)&Bs[srow * LDS_STRIDE + scol] = b0;
        *(short8*)&Bs[(srow + 64) * LDS_STRIDE + scol] = b1;
        __syncthreads();

        short8 af[4], bf[4];
#pragma unroll
        for (int i = 0; i < 4; i++)
            af[i] = *(const short8*)&As[(wm + i * 16 + l16) * LDS_STRIDE + quad * 8];
#pragma unroll
        for (int j = 0; j < 4; j++)
            bf[j] = *(const short8*)&Bs[(wn + j * 16 + l16) * LDS_STRIDE + quad * 8];
#pragma unroll
        for (int i = 0; i < 4; i++)
#pragma unroll
            for (int j = 0; j < 4; j++)
                acc[i][j] = __builtin_amdgcn_mfma_f32_16x16x32_bf16(af[i], bf[j], acc[i][j], 0, 0, 0);
    }

#pragma unroll
    for (int i = 0; i < 4; i++) {
#pragma unroll
        for (int j = 0; j < 4; j++) {
#pragma unroll
            for (int r = 0; r < 4; r++) {
                const int row = m0 + wm + i * 16 + quad * 4 + r;  // M index
                const int col = n0 + wn + j * 16 + l16;           // N index
                float v = acc[i][j][r] + bias[col];
                if (MODE == 0) {
                    // col in [0,3072): h=col/192, rr=col%192, sel=rr/64, d=rr%64
                    const int h  = col / 192;
                    const int rr = col - h * 192;
                    const int sel = rr >> 6;
                    const int d   = rr & 63;
                    const int b = row >> 11;      // T = 2048
                    const int t = row & 2047;
                    const size_t idx = (((size_t)(b * 16 + h)) * 2048 + t) * 64 + d;
                    if (sel == 0) {
                        Cq[idx] = f32_to_bf16(v * 0.125f);  // fold softmax scale (exact)
                    } else if (sel == 1) {
                        Ck[idx] = f32_to_bf16(v);
                    } else {
                        Cv[idx] = f32_to_bf16(v);
                    }
                } else {
                    Cout[(size_t)row * N + col] = v;
                }
            }
        }
    }
}

// Vector-ALU causal flash attention. One block = 256 threads = (bh, 64-row Q tile).
// Thread (qr = tid>>2, g = tid&3): scores for s in [16g,16g+16), output d in [16g,16g+16).
__global__ __launch_bounds__(256, 2) void attn_kernel(
    const ushort* __restrict__ Q, const ushort* __restrict__ K,
    const ushort* __restrict__ V, ushort* __restrict__ O)
{
    const int bh = blockIdx.x >> 5;  // 0..31
    const int qt = blockIdx.x & 31;  // 0..31
    const int t0 = qt * 64;
    const int tid = threadIdx.x;
    const int qr = tid >> 2;  // 0..63
    const int g  = tid & 3;   // 0..3

    __shared__ float Qs[64][65];
    __shared__ float Ks[64][65];
    __shared__ float Ps[64][65];
    __shared__ ushort Vs[64][64];

    const size_t base = (size_t)bh * 2048 * 64;
    const int t_row = t0 + qr;

    // load Q tile (already scaled by 0.125)
    {
        const ushort* qp = Q + base + (size_t)t_row * 64 + g * 16;
        const short8 q8a = *(const short8*)qp;
        const short8 q8b = *(const short8*)(qp + 8);
#pragma unroll
        for (int i = 0; i < 8; i++) Qs[qr][g * 16 + i]     = bf16_to_f32((unsigned short)q8a[i]);
#pragma unroll
        for (int i = 0; i < 8; i++) Qs[qr][g * 16 + 8 + i] = bf16_to_f32((unsigned short)q8b[i]);
    }

    float o[16];
#pragma unroll
    for (int i = 0; i < 16; i++) o[i] = 0.0f;
    float m = -1e30f, l = 0.0f;

    for (int s0 = 0; s0 <= t0; s0 += 64) {
        {
            const ushort* kp = K + base + (size_t)(s0 + qr) * 64 + g * 16;
            const ushort* vp = V + base + (size_t)(s0 + qr) * 64 + g * 16;
            const short8 k8a = *(const short8*)kp;
            const short8 k8b = *(const short8*)(kp + 8);
            const short8 v8a = *(const short8*)vp;
            const short8 v8b = *(const short8*)(vp + 8);
            __syncthreads();  // prev iter's LDS reads done (also covers Qs on iter 0)
#pragma unroll
            for (int i = 0; i < 8; i++) {
                Ks[qr][g * 16 + i]     = bf16_to_f32((unsigned short)k8a[i]);
                Ks[qr][g * 16 + 8 + i] = bf16_to_f32((unsigned short)k8b[i]);
            }
            *(short8*)&Vs[qr][g * 16]     = v8a;
            *(short8*)&Vs[qr][g * 16 + 8] = v8b;
            __syncthreads();
        }

        float sc[16];
#pragma unroll
        for (int ss = 0; ss < 16; ss++) sc[ss] = 0.0f;
        for (int i = 0; i < 64; i++) {
            const float qv = Qs[qr][i];
#pragma unroll
            for (int ss = 0; ss < 16; ss++) sc[ss] += qv * Ks[g * 16 + ss][i];
        }

        const bool diag = (s0 == t0);
        float tmax = -1e30f;
#pragma unroll
        for (int ss = 0; ss < 16; ss++) {
            const int s = s0 + g * 16 + ss;
            if (diag && s > t_row) sc[ss] = -1e30f;
            tmax = fmaxf(tmax, sc[ss]);
        }
        tmax = fmaxf(tmax, __shfl_xor(tmax, 1));
        tmax = fmaxf(tmax, __shfl_xor(tmax, 2));

        const float mnew = fmaxf(m, tmax);
        const float alpha = __expf(m - mnew);
        float psum = 0.0f;
#pragma unroll
        for (int ss = 0; ss < 16; ss++) {
            const float p = __expf(sc[ss] - mnew);
            Ps[qr][g * 16 + ss] = p;
            psum += p;
        }
        psum += __shfl_xor(psum, 1);
        psum += __shfl_xor(psum, 2);
        l = l * alpha + psum;
        m = mnew;
#pragma unroll
        for (int i = 0; i < 16; i++) o[i] *= alpha;
        __syncthreads();  // Ps visible to all

        for (int s = 0; s < 64; s++) {
            const float p = Ps[qr][s];
#pragma unroll
            for (int i = 0; i < 16; i++)
                o[i] += p * bf16_to_f32(Vs[s][g * 16 + i]);
        }
        // next-iter top __syncthreads protects Ks/Vs/Ps from overwrite
    }

    const float inv_l = 1.0f / l;
    const int b = bh >> 4, h = bh & 15;
    ushort* op = O + ((size_t)(b * 2048 + t_row)) * 1024 + h * 64 + g * 16;
#pragma unroll
    for (int i = 0; i < 16; i++) op[i] = f32_to_bf16(o[i] * inv_l);
}

extern "C" void kernel_launch(void* const* d_in, const int* in_sizes, int n_in,
                              void* d_out, int out_size, void* d_ws, size_t ws_size,
                              hipStream_t stream) {
    const float* x    = (const float*)d_in[0];
    const float* Wqkv = (const float*)d_in[1];
    const float* bqkv = (const float*)d_in[2];
    const float* Wout = (const float*)d_in[3];
    const float* bout = (const float*)d_in[4];
    float* out = (float*)d_out;

    char* ws = (char*)d_ws;
    ushort* Q = (ushort*)(ws + (size_t)0);
    ushort* K = (ushort*)(ws + (size_t)8 * 1024 * 1024);
    ushort* V = (ushort*)(ws + (size_t)16 * 1024 * 1024);
    ushort* O = (ushort*)(ws + (size_t)24 * 1024 * 1024);

    const dim3 blk(256);
    // QKV: M=4096, N=3072, K=1024
    gemm_bt<0, 1><<<dim3(32, 24), blk, 0, stream>>>(x, Wqkv, bqkv, Q, K, V, nullptr,
                                                    4096, 3072, 1024);
    // attention: 32 bh * 32 q-tiles
    attn_kernel<<<dim3(1024), blk, 0, stream>>>(Q, K, V, O);
    // out-proj: M=4096, N=1024, K=1024
    gemm_bt<1, 0><<<dim3(32, 8), blk, 0, stream>>>(O, Wout, bout, nullptr, nullptr, nullptr,
                                                   out, 4096, 1024, 1024);
}

// Round 4
// 319.729 us; speedup vs baseline: 4.4164x; 4.4164x over previous
//
#include <hip/hip_runtime.h>
#include <hip/hip_bf16.h>
#include <cstdint>

// ---------------------------------------------------------------------------
// MultiHeadAttention: B=2, T=2048, D=1024, H=16, hd=64, causal.
// Inputs (fp32): x[B,T,D], W_qkv[3D,D], b_qkv[3D], W_out[D,D], b_out[D]
// out (fp32): [B,T,D]
// ws: Q[2,16,2048,64] bf16 @0 (pre-scaled 0.125*log2e), K[bh][t][64] @8MB,
//     Vt[bh][64][t] @16MB (transposed!), O[B,T,D] bf16 @24MB
// ---------------------------------------------------------------------------

using short8  = __attribute__((ext_vector_type(8))) short;
using floatx4 = __attribute__((ext_vector_type(4))) float;

#define LDS_STRIDE 40  // GEMM tiles: 32+8 pad, 2-way bank alias (free)

__device__ __forceinline__ float bf16_to_f32(unsigned short u) {
    union { unsigned int i; float f; } v; v.i = ((unsigned int)u) << 16; return v.f;
}
__device__ __forceinline__ unsigned short f32_to_bf16(float f) {
    union { float f; unsigned int i; } v; v.f = f;
    unsigned int x = v.i;
    unsigned int r = x + 0x7FFFu + ((x >> 16) & 1u);  // RNE
    return (unsigned short)(r >> 16);
}
__device__ __forceinline__ short8 cvt8(const float* __restrict__ p) {
    const float4 f0 = *(const float4*)p;
    const float4 f1 = *(const float4*)(p + 4);
    short8 r;
    r[0] = (short)f32_to_bf16(f0.x); r[1] = (short)f32_to_bf16(f0.y);
    r[2] = (short)f32_to_bf16(f0.z); r[3] = (short)f32_to_bf16(f0.w);
    r[4] = (short)f32_to_bf16(f1.x); r[5] = (short)f32_to_bf16(f1.y);
    r[6] = (short)f32_to_bf16(f1.z); r[7] = (short)f32_to_bf16(f1.w);
    return r;
}

// 1/sqrt(64) * log2(e): scores come out of QK^T already in log2 domain
#define Q_PRESCALE 0.1803368801111204f

// C[M,N] = A[M,K] @ W[N,K]^T + bias[N].  W,bias fp32; A fp32 (AFP32=1) or bf16.
// MODE 0: scatter Q[bh][t][d] (scaled), K[bh][t][d], Vt[bh][d][t]  (all bf16)
// MODE 1: fp32 store to Cout[M,N]
template <int MODE, int AFP32>
__global__ __launch_bounds__(256, 2) void gemm_bt(
    const void* __restrict__ Av, const float* __restrict__ W,
    const float* __restrict__ bias,
    ushort* __restrict__ Cq, ushort* __restrict__ Ck, ushort* __restrict__ Cv,
    float* __restrict__ Cout, int M, int N, int K)
{
    __shared__ __align__(16) ushort As[128 * LDS_STRIDE];
    __shared__ __align__(16) ushort Bs[128 * LDS_STRIDE];

    const int tid  = threadIdx.x;
    const int lane = tid & 63;
    const int wave = tid >> 6;
    const int wm = (wave >> 1) * 64;
    const int wn = (wave & 1) * 64;
    const int m0 = blockIdx.x * 128;
    const int n0 = blockIdx.y * 128;
    const int quad = lane >> 4;
    const int l16  = lane & 15;

    floatx4 acc[4][4];
#pragma unroll
    for (int i = 0; i < 4; i++)
#pragma unroll
        for (int j = 0; j < 4; j++) acc[i][j] = (floatx4)0.0f;

    const int srow = tid >> 2;       // 0..63
    const int scol = (tid & 3) * 8;  // 0,8,16,24

    for (int k0 = 0; k0 < K; k0 += 32) {
        short8 a0, a1;
        if (AFP32) {
            const float* A = (const float*)Av;
            a0 = cvt8(A + (size_t)(m0 + srow) * K + k0 + scol);
            a1 = cvt8(A + (size_t)(m0 + srow + 64) * K + k0 + scol);
        } else {
            const ushort* A = (const ushort*)Av;
            a0 = *(const short8*)(A + (size_t)(m0 + srow) * K + k0 + scol);
            a1 = *(const short8*)(A + (size_t)(m0 + srow + 64) * K + k0 + scol);
        }
        const short8 b0 = cvt8(W + (size_t)(n0 + srow) * K + k0 + scol);
        const short8 b1 = cvt8(W + (size_t)(n0 + srow + 64) * K + k0 + scol);
        __syncthreads();  // previous iter's LDS reads done
        *(short8*)&As[srow * LDS_STRIDE + scol] = a0;
        *(short8*)&As[(srow + 64) * LDS_STRIDE + scol] = a1;
        *(short8*)&Bs[srow * LDS_STRIDE + scol] = b0;
        *(short8*)&Bs[(srow + 64) * LDS_STRIDE + scol] = b1;
        __syncthreads();

        short8 af[4], bf[4];
#pragma unroll
        for (int i = 0; i < 4; i++)
            af[i] = *(const short8*)&As[(wm + i * 16 + l16) * LDS_STRIDE + quad * 8];
#pragma unroll
        for (int j = 0; j < 4; j++)
            bf[j] = *(const short8*)&Bs[(wn + j * 16 + l16) * LDS_STRIDE + quad * 8];
#pragma unroll
        for (int i = 0; i < 4; i++)
#pragma unroll
            for (int j = 0; j < 4; j++)
                acc[i][j] = __builtin_amdgcn_mfma_f32_16x16x32_bf16(af[i], bf[j], acc[i][j], 0, 0, 0);
    }

#pragma unroll
    for (int i = 0; i < 4; i++) {
#pragma unroll
        for (int j = 0; j < 4; j++) {
#pragma unroll
            for (int r = 0; r < 4; r++) {
                const int row = m0 + wm + i * 16 + quad * 4 + r;  // M index
                const int col = n0 + wn + j * 16 + l16;           // N index
                float v = acc[i][j][r] + bias[col];
                if (MODE == 0) {
                    // col in [0,3072): h=col/192, rr=col%192, sel=rr/64, d=rr%64
                    const int h  = col / 192;
                    const int rr = col - h * 192;
                    const int sel = rr >> 6;
                    const int d   = rr & 63;
                    const int b = row >> 11;      // T = 2048
                    const int t = row & 2047;
                    if (sel == 0) {
                        const size_t idx = (((size_t)(b * 16 + h)) * 2048 + t) * 64 + d;
                        Cq[idx] = f32_to_bf16(v * Q_PRESCALE);
                    } else if (sel == 1) {
                        const size_t idx = (((size_t)(b * 16 + h)) * 2048 + t) * 64 + d;
                        Ck[idx] = f32_to_bf16(v);
                    } else {
                        // V transposed: [bh][d][t]
                        const size_t idx = (((size_t)(b * 16 + h)) * 64 + d) * 2048 + t;
                        Cv[idx] = f32_to_bf16(v);
                    }
                } else {
                    Cout[(size_t)row * N + col] = v;
                }
            }
        }
    }
}

// MFMA causal flash attention, barrier-free.
// Block = 4 waves; wave owns 16 q-rows (qbase..qbase+15), loops 64-key tiles.
// Q[bh][t][64] (prescaled), K[bh][t][64], Vt[bh][64][t]; O[b][t][1024] bf16.
__global__ __launch_bounds__(256, 4) void attn_mfma(
    const ushort* __restrict__ Q, const ushort* __restrict__ K,
    const ushort* __restrict__ Vt, ushort* __restrict__ O)
{
    const int bid  = blockIdx.x;
    const int bh   = bid & 31;          // inner: spreads bh across XCDs
    const int qt   = 31 - (bid >> 5);   // heavy q-tiles dispatched first
    const int tid  = threadIdx.x;
    const int wave = tid >> 6;
    const int lane = tid & 63;
    const int quad = lane >> 4;
    const int l16  = lane & 15;
    const int qbase = qt * 64 + wave * 16;

    // per-wave P buffer: 16 rows x 64 keys, stride 72 (2-way alias only)
    __shared__ __align__(16) ushort Pl[4][16 * 72];
    ushort* Pw = &Pl[wave][0];

    const size_t kbase = (size_t)bh * 2048 * 64;

    // Q A-fragments, straight from global (16B/lane, stays in VGPRs)
    const ushort* qp = Q + kbase + (size_t)(qbase + l16) * 64 + quad * 8;
    const short8 qf0 = *(const short8*)qp;
    const short8 qf1 = *(const short8*)(qp + 32);

    floatx4 acc[4];
#pragma unroll
    for (int d = 0; d < 4; d++) acc[d] = (floatx4)0.0f;
    float mrow[4], lrow[4];
#pragma unroll
    for (int r = 0; r < 4; r++) { mrow[r] = -1e30f; lrow[r] = 0.0f; }

    const ushort* vbase = Vt + (size_t)bh * 64 * 2048 + (size_t)l16 * 2048;
    const int send = qt * 64;

    for (int s0 = 0; s0 <= send; s0 += 64) {
        // ---- S = Q K^T (scores in log2 domain via Q prescale) ----
        const ushort* kp = K + kbase + (size_t)(s0 + l16) * 64 + quad * 8;
        floatx4 sacc[4];
#pragma unroll
        for (int j = 0; j < 4; j++) {
            const short8 kf0 = *(const short8*)(kp + j * 1024);
            const short8 kf1 = *(const short8*)(kp + j * 1024 + 32);
            floatx4 t = (floatx4)0.0f;
            t = __builtin_amdgcn_mfma_f32_16x16x32_bf16(qf0, kf0, t, 0, 0, 0);
            t = __builtin_amdgcn_mfma_f32_16x16x32_bf16(qf1, kf1, t, 0, 0, 0);
            sacc[j] = t;
        }

        // ---- causal mask (only the diagonal tile; wave-uniform branch) ----
        if (s0 + 63 > qbase) {
#pragma unroll
            for (int j = 0; j < 4; j++) {
                const int key = s0 + j * 16 + l16;
#pragma unroll
                for (int r = 0; r < 4; r++) {
                    if (key > qbase + quad * 4 + r) sacc[j][r] = -1e30f;
                }
            }
        }

        // ---- online softmax (row = quad*4+r, cols across l16 and j) ----
        float rmax[4];
#pragma unroll
        for (int r = 0; r < 4; r++)
            rmax[r] = fmaxf(fmaxf(sacc[0][r], sacc[1][r]), fmaxf(sacc[2][r], sacc[3][r]));
#pragma unroll
        for (int msk = 1; msk <= 8; msk <<= 1)
#pragma unroll
            for (int r = 0; r < 4; r++)
                rmax[r] = fmaxf(rmax[r], __shfl_xor(rmax[r], msk));

        float alpha[4], rsum[4];
#pragma unroll
        for (int r = 0; r < 4; r++) {
            const float mnew = fmaxf(mrow[r], rmax[r]);
            alpha[r] = exp2f(mrow[r] - mnew);
            mrow[r] = mnew;
            rsum[r] = 0.0f;
        }
#pragma unroll
        for (int j = 0; j < 4; j++)
#pragma unroll
            for (int r = 0; r < 4; r++) {
                const float p = exp2f(sacc[j][r] - mrow[r]);
                sacc[j][r] = p;
                rsum[r] += p;
            }
#pragma unroll
        for (int msk = 1; msk <= 8; msk <<= 1)
#pragma unroll
            for (int r = 0; r < 4; r++)
                rsum[r] += __shfl_xor(rsum[r], msk);
#pragma unroll
        for (int r = 0; r < 4; r++) lrow[r] = lrow[r] * alpha[r] + rsum[r];

        // ---- P: C-layout -> A-layout via per-wave LDS (same-wave, no barrier) ----
#pragma unroll
        for (int j = 0; j < 4; j++)
#pragma unroll
            for (int r = 0; r < 4; r++)
                Pw[(quad * 4 + r) * 72 + j * 16 + l16] = f32_to_bf16(sacc[j][r]);

#pragma unroll
        for (int d = 0; d < 4; d++)
#pragma unroll
            for (int r = 0; r < 4; r++) acc[d][r] *= alpha[r];

        const short8 pf0 = *(const short8*)&Pw[l16 * 72 + quad * 8];
        const short8 pf1 = *(const short8*)&Pw[l16 * 72 + 32 + quad * 8];

        // ---- O += P V  (Vt[d][t]: contiguous 16B key-runs per lane) ----
        const ushort* vp = vbase + s0 + quad * 8;
#pragma unroll
        for (int d = 0; d < 4; d++) {
            const short8 vf0 = *(const short8*)(vp + d * 16 * 2048);
            const short8 vf1 = *(const short8*)(vp + d * 16 * 2048 + 32);
            acc[d] = __builtin_amdgcn_mfma_f32_16x16x32_bf16(pf0, vf0, acc[d], 0, 0, 0);
            acc[d] = __builtin_amdgcn_mfma_f32_16x16x32_bf16(pf1, vf1, acc[d], 0, 0, 0);
        }
    }

    // ---- epilogue: O[b][t][h*64+d] bf16 ----
    const int b = bh >> 4, h = bh & 15;
    float inv[4];
#pragma unroll
    for (int r = 0; r < 4; r++) inv[r] = 1.0f / lrow[r];
#pragma unroll
    for (int d = 0; d < 4; d++)
#pragma unroll
        for (int r = 0; r < 4; r++)
            O[(size_t)(b * 2048 + qbase + quad * 4 + r) * 1024 + h * 64 + d * 16 + l16] =
                f32_to_bf16(acc[d][r] * inv[r]);
}

extern "C" void kernel_launch(void* const* d_in, const int* in_sizes, int n_in,
                              void* d_out, int out_size, void* d_ws, size_t ws_size,
                              hipStream_t stream) {
    const float* x    = (const float*)d_in[0];
    const float* Wqkv = (const float*)d_in[1];
    const float* bqkv = (const float*)d_in[2];
    const float* Wout = (const float*)d_in[3];
    const float* bout = (const float*)d_in[4];
    float* out = (float*)d_out;

    char* ws = (char*)d_ws;
    ushort* Q  = (ushort*)(ws + (size_t)0);
    ushort* K  = (ushort*)(ws + (size_t)8 * 1024 * 1024);
    ushort* Vt = (ushort*)(ws + (size_t)16 * 1024 * 1024);
    ushort* O  = (ushort*)(ws + (size_t)24 * 1024 * 1024);

    const dim3 blk(256);
    // QKV: M=4096, N=3072, K=1024
    gemm_bt<0, 1><<<dim3(32, 24), blk, 0, stream>>>(x, Wqkv, bqkv, Q, K, Vt, nullptr,
                                                    4096, 3072, 1024);
    // attention: 32 bh x 32 q-tiles, barrier-free MFMA flash
    attn_mfma<<<dim3(1024), blk, 0, stream>>>(Q, K, Vt, O);
    // out-proj: M=4096, N=1024, K=1024
    gemm_bt<1, 0><<<dim3(32, 8), blk, 0, stream>>>(O, Wout, bout, nullptr, nullptr, nullptr,
                                                   out, 4096, 1024, 1024);
}